// Round 4
// baseline (294.249 us; speedup 1.0000x reference)
//
#include <hip/hip_runtime.h>
#include <hip/hip_bf16.h>

// Causal fused attention (flash-style), S=2048, B=2, H=16, D=64.
// Inputs: FP32 [S,B,H,D] (bf16-rounded values in fp32 storage, per harness).
// Output: FP32 [S,B,H*D].  elem(s,bh,d) = s*2048 + bh*64 + d for both.
// Compute: fp32->bf16 cast, MFMA 16x16x32_bf16, fp32 softmax/accum.

typedef __attribute__((ext_vector_type(8))) short bf16x8;   // 8 bf16 = 4 VGPRs
typedef __attribute__((ext_vector_type(4))) float floatx4;  // MFMA C/D

#define ROWSTR 2048      // B*H*D element stride between consecutive s
#define SCALE  0.125f    // 1/sqrt(64)
#define MASKV  (-10000.0f)
#define QT     64        // q rows per workgroup (16 per wave)
#define KT     32        // kv positions per tile
#define KSTR   72        // LDS K row stride (shorts; 144B rows, 2-way alias = free)
#define VTSTR  40        // LDS V^T row stride (80B rows)
#define PSTR   40        // LDS P row stride

__device__ __forceinline__ short f2bf(float x) {
  __hip_bfloat16 h = __float2bfloat16(x);
  return __builtin_bit_cast(short, h);
}

__global__ __launch_bounds__(256)
void fattn_kernel(const float* __restrict__ Q,
                  const float* __restrict__ K,
                  const float* __restrict__ V,
                  float* __restrict__ O) {
  __shared__ __align__(16) __hip_bfloat16 lds_k[KT * KSTR];      // 4608 B
  __shared__ __align__(16) __hip_bfloat16 lds_vt[64 * VTSTR];    // 5120 B
  __shared__ __align__(16) __hip_bfloat16 lds_p[4 * 16 * PSTR];  // 5120 B

  const int tid  = threadIdx.x;
  const int wave = tid >> 6;
  const int lane = tid & 63;
  const int l16  = lane & 15;
  const int quad = lane >> 4;

  const int bh = blockIdx.y;                 // 0..31
  const int qb = blockIdx.x * QT;            // q tile base
  const size_t base = (size_t)bh * 64;

  // ---- Q fragments (A-layout: m = l16, k = quad*8 + j), two 32-wide d-chunks
  const int qrow = qb + wave * 16 + l16;
  bf16x8 qf0, qf1;
  {
    const float* qp = Q + (size_t)qrow * ROWSTR + base + quad * 8;
    float4 a0 = *(const float4*)(qp);
    float4 a1 = *(const float4*)(qp + 4);
    float4 b0 = *(const float4*)(qp + 32);
    float4 b1 = *(const float4*)(qp + 36);
    qf0[0]=f2bf(a0.x); qf0[1]=f2bf(a0.y); qf0[2]=f2bf(a0.z); qf0[3]=f2bf(a0.w);
    qf0[4]=f2bf(a1.x); qf0[5]=f2bf(a1.y); qf0[6]=f2bf(a1.z); qf0[7]=f2bf(a1.w);
    qf1[0]=f2bf(b0.x); qf1[1]=f2bf(b0.y); qf1[2]=f2bf(b0.z); qf1[3]=f2bf(b0.w);
    qf1[4]=f2bf(b1.x); qf1[5]=f2bf(b1.y); qf1[6]=f2bf(b1.z); qf1[7]=f2bf(b1.w);
  }

  floatx4 o0 = {0.f,0.f,0.f,0.f}, o1 = o0, o2 = o0, o3 = o0;
  float mrow[4] = {MASKV, MASKV, MASKV, MASKV};
  float lrow[4] = {0.f, 0.f, 0.f, 0.f};

  const int wave_qmax = qb + wave * 16 + 15;
  const int t_end = qb + QT;                 // causal: no kv tile beyond block's last row

  // staging decomposition: 256 threads cover 32 rows x 8 col-groups of 8
  const int srow = tid >> 3;                 // kv row 0..31
  const int scol = (tid & 7) * 8;            // d col base 0..56

  for (int t0 = 0; t0 < t_end; t0 += KT) {
    __syncthreads();  // previous tile's compute done before overwrite
    // ---- stage K tile [KT][64] row-major bf16, padded
    {
      const float* kp = K + (size_t)(t0 + srow) * ROWSTR + base + scol;
      float4 k0 = *(const float4*)(kp);
      float4 k1 = *(const float4*)(kp + 4);
      union { short s[8]; uint4 u; } t8;
      t8.s[0]=f2bf(k0.x); t8.s[1]=f2bf(k0.y); t8.s[2]=f2bf(k0.z); t8.s[3]=f2bf(k0.w);
      t8.s[4]=f2bf(k1.x); t8.s[5]=f2bf(k1.y); t8.s[6]=f2bf(k1.z); t8.s[7]=f2bf(k1.w);
      *(uint4*)((short*)lds_k + srow * KSTR + scol) = t8.u;
    }
    // ---- stage V^T [64][KT] bf16 (transpose during staging)
    {
      const float* vp = V + (size_t)(t0 + srow) * ROWSTR + base + scol;
      float4 v0 = *(const float4*)(vp);
      float4 v1 = *(const float4*)(vp + 4);
      float vv[8] = { v0.x, v0.y, v0.z, v0.w, v1.x, v1.y, v1.z, v1.w };
      short* dst = (short*)lds_vt;
#pragma unroll
      for (int j = 0; j < 8; ++j)
        dst[(scol + j) * VTSTR + srow] = f2bf(vv[j]);
    }
    __syncthreads();

    if (t0 <= wave_qmax) {   // wave-uniform predicate; barriers stay outside
      // ---- K fragments (B-layout over K^T: n = l16, k(d) = quad*8+j)
      const short* kb = (const short*)lds_k;
      bf16x8 kf00 = *(const bf16x8*)(kb + l16 * KSTR + quad * 8);
      bf16x8 kf01 = *(const bf16x8*)(kb + l16 * KSTR + 32 + quad * 8);
      bf16x8 kf10 = *(const bf16x8*)(kb + (16 + l16) * KSTR + quad * 8);
      bf16x8 kf11 = *(const bf16x8*)(kb + (16 + l16) * KSTR + 32 + quad * 8);

      floatx4 z = {0.f,0.f,0.f,0.f};
      floatx4 sc0 = __builtin_amdgcn_mfma_f32_16x16x32_bf16(qf0, kf00, z, 0, 0, 0);
      sc0 = __builtin_amdgcn_mfma_f32_16x16x32_bf16(qf1, kf01, sc0, 0, 0, 0);
      floatx4 sc1 = __builtin_amdgcn_mfma_f32_16x16x32_bf16(qf0, kf10, z, 0, 0, 0);
      sc1 = __builtin_amdgcn_mfma_f32_16x16x32_bf16(qf1, kf11, sc1, 0, 0, 0);

      // ---- online softmax (C-layout: col = l16, row = quad*4 + r)
      const int tc0 = t0 + l16;
      const int tc1 = t0 + 16 + l16;
      const int rbase = qb + wave * 16 + quad * 4;
      float p0[4], p1[4], alpha[4];
#pragma unroll
      for (int r = 0; r < 4; ++r) {
        const int s = rbase + r;
        float v0 = (tc0 <= s) ? sc0[r] * SCALE : MASKV;  // finite fill, like ref
        float v1 = (tc1 <= s) ? sc1[r] * SCALE : MASKV;
        float mx = fmaxf(v0, v1);
#pragma unroll
        for (int off = 1; off < 16; off <<= 1)
          mx = fmaxf(mx, __shfl_xor(mx, off));
        const float mnew = fmaxf(mrow[r], mx);           // always finite
        const float a  = __expf(mrow[r] - mnew);         // finite arg <= 0
        const float e0 = __expf(v0 - mnew);              // masked -> underflow 0
        const float e1 = __expf(v1 - mnew);
        float rs = e0 + e1;
#pragma unroll
        for (int off = 1; off < 16; off <<= 1)
          rs += __shfl_xor(rs, off);
        lrow[r] = lrow[r] * a + rs;
        mrow[r] = mnew;
        alpha[r] = a;
        p0[r] = e0;
        p1[r] = e1;
      }

      // ---- P: C-layout -> LDS -> A-layout (per-wave region, padded)
      __hip_bfloat16* pw = lds_p + wave * (16 * PSTR);
#pragma unroll
      for (int r = 0; r < 4; ++r) {
        const int row = quad * 4 + r;
        pw[row * PSTR + l16]      = __float2bfloat16(p0[r]);
        pw[row * PSTR + 16 + l16] = __float2bfloat16(p1[r]);
      }
      asm volatile("s_waitcnt lgkmcnt(0)" ::: "memory");  // per-wave LDS RAW

      bf16x8 pf = *(const bf16x8*)((const short*)pw + l16 * PSTR + quad * 8);

      const short* vb = (const short*)lds_vt;
      bf16x8 vf0 = *(const bf16x8*)(vb + (l16)      * VTSTR + quad * 8);
      bf16x8 vf1 = *(const bf16x8*)(vb + (16 + l16) * VTSTR + quad * 8);
      bf16x8 vf2 = *(const bf16x8*)(vb + (32 + l16) * VTSTR + quad * 8);
      bf16x8 vf3 = *(const bf16x8*)(vb + (48 + l16) * VTSTR + quad * 8);

#pragma unroll
      for (int r = 0; r < 4; ++r) {
        o0[r] *= alpha[r]; o1[r] *= alpha[r];
        o2[r] *= alpha[r]; o3[r] *= alpha[r];
      }
      o0 = __builtin_amdgcn_mfma_f32_16x16x32_bf16(pf, vf0, o0, 0, 0, 0);
      o1 = __builtin_amdgcn_mfma_f32_16x16x32_bf16(pf, vf1, o1, 0, 0, 0);
      o2 = __builtin_amdgcn_mfma_f32_16x16x32_bf16(pf, vf2, o2, 0, 0, 0);
      o3 = __builtin_amdgcn_mfma_f32_16x16x32_bf16(pf, vf3, o3, 0, 0, 0);
    }
  }

  // ---- epilogue: divide by l, write FP32 (d_out is float*, per reference)
#pragma unroll
  for (int r = 0; r < 4; ++r) {
    const float inv = 1.0f / lrow[r];
    const int s = qb + wave * 16 + quad * 4 + r;
    float* op = O + (size_t)s * ROWSTR + base;
    op[l16]      = o0[r] * inv;
    op[16 + l16] = o1[r] * inv;
    op[32 + l16] = o2[r] * inv;
    op[48 + l16] = o3[r] * inv;
  }
}

extern "C" void kernel_launch(void* const* d_in, const int* in_sizes, int n_in,
                              void* d_out, int out_size, void* d_ws, size_t ws_size,
                              hipStream_t stream) {
  (void)in_sizes; (void)n_in; (void)out_size; (void)d_ws; (void)ws_size;
  const float* Q = (const float*)d_in[0];
  const float* K = (const float*)d_in[1];
  const float* V = (const float*)d_in[2];
  float* O = (float*)d_out;

  dim3 grid(2048 / QT, 32, 1);   // 32 q-tiles x 32 (b,h) pairs = 1024 blocks
  dim3 block(256, 1, 1);
  fattn_kernel<<<grid, block, 0, stream>>>(Q, K, V, O);
}

// Round 6
// 170.965 us; speedup vs baseline: 1.7211x; 1.7211x over previous
//
#include <hip/hip_runtime.h>
#include <hip/hip_bf16.h>

// Causal fused attention (flash-style), S=2048, B=2, H=16, D=64.
// Inputs: FP32 [S,B,H,D]; Output: FP32 [S,B,H*D]; elem(s,bh,d)=s*2048+bh*64+d.
//
// Structure (round 6 == round 5 with exp2 intrinsic fixed):
//  - S^T = K·Q^T via mfma(kf, qf): C-layout col=l16 -> q, row=quad*4+r -> t.
//    Softmax rows are per-lane => no per-tile cross-lane reductions.
//  - Fixed-shift exp (no running max): p = exp2(s*SCALE*log2e - 17.31)
//    via __builtin_amdgcn_exp2f (one v_exp_f32). Ratios exactly preserved;
//    l accumulated per-lane, reduced once in the epilogue.
//  - O^T = V^T·P accumulated in C-layout; epilogue float4 stores per q-row.
//  - Register prefetch of next K/V tile overlaps global latency with compute.
//  - V^T staged column-wise (coalesced loads, b64 LDS writes, uniform banks).
//  - Block order reversed: longest causal blocks first (tail kill).

typedef __attribute__((ext_vector_type(8))) short bf16x8;
typedef __attribute__((ext_vector_type(4))) float floatx4;

#define ROWSTR 2048
#define C1 (0.125f * 1.44269504088896f)   // SCALE * log2(e)
#define C0 (-17.3123404906676f)           // -12 * log2(e) (fixed shift)
#define QT 64
#define KT 32
#define KSTR  68   // K row stride (shorts): word-stride 34 -> uniform banks
#define VTSTR 36   // V^T row stride: word-stride 18 -> uniform banks, 8B aligned
#define PSTR  36   // P row stride: same property

__device__ __forceinline__ short f2bf(float x) {
  return __builtin_bit_cast(short, __float2bfloat16(x));
}
__device__ __forceinline__ unsigned pk2(float a, float b) {
  return (unsigned)(unsigned short)f2bf(a) |
         ((unsigned)(unsigned short)f2bf(b) << 16);
}
__device__ __forceinline__ bf16x8 ld8(const short* p) {  // two ds_read_b64
  union { bf16x8 v; uint2 u[2]; } r;
  r.u[0] = *(const uint2*)(p);
  r.u[1] = *(const uint2*)(p + 4);
  return r.v;
}

__global__ __launch_bounds__(256)
void fattn_kernel(const float* __restrict__ Q,
                  const float* __restrict__ K,
                  const float* __restrict__ V,
                  float* __restrict__ O) {
  __shared__ __align__(16) short lds_k[KT * KSTR];       // 4352 B
  __shared__ __align__(16) short lds_vt[64 * VTSTR];     // 4608 B
  __shared__ __align__(16) short lds_p[4 * 16 * PSTR];   // 4608 B

  const int tid  = threadIdx.x;
  const int wave = tid >> 6;
  const int lane = tid & 63;
  const int l16  = lane & 15;
  const int quad = lane >> 4;

  const int bh    = blockIdx.y;
  const int qtile = gridDim.x - 1 - blockIdx.x;  // longest blocks dispatch first
  const int qb    = qtile * QT;
  const size_t base = (size_t)bh * 64;

  // Q fragments (B-operand of S^T: n=l16 -> q, k=quad*8+j -> d)
  const int qrow = qb + wave * 16 + l16;
  bf16x8 qf0, qf1;
  {
    const float* qp = Q + (size_t)qrow * ROWSTR + base + quad * 8;
    float4 a0 = *(const float4*)(qp);
    float4 a1 = *(const float4*)(qp + 4);
    float4 b0 = *(const float4*)(qp + 32);
    float4 b1 = *(const float4*)(qp + 36);
    qf0[0]=f2bf(a0.x); qf0[1]=f2bf(a0.y); qf0[2]=f2bf(a0.z); qf0[3]=f2bf(a0.w);
    qf0[4]=f2bf(a1.x); qf0[5]=f2bf(a1.y); qf0[6]=f2bf(a1.z); qf0[7]=f2bf(a1.w);
    qf1[0]=f2bf(b0.x); qf1[1]=f2bf(b0.y); qf1[2]=f2bf(b0.z); qf1[3]=f2bf(b0.w);
    qf1[4]=f2bf(b1.x); qf1[5]=f2bf(b1.y); qf1[6]=f2bf(b1.z); qf1[7]=f2bf(b1.w);
  }

  floatx4 o0 = {0.f,0.f,0.f,0.f}, o1 = o0, o2 = o0, o3 = o0;  // O^T chunks
  float lsum = 0.f;                                           // per-lane partial l

  const int wave_qmax = qb + wave * 16 + 15;
  const int t_end = qb + QT;

  // staging roles: K row-wise (32 rows x 8 col-groups), V column-wise (64 d x 4 t-groups)
  const int krow = tid >> 3;            // 0..31
  const int kcol = (tid & 7) * 8;       // 0..56
  const int dcol = tid & 63;            // V^T row (d)
  const int tg   = tid >> 6;            // t-group of 8 (== wave)

  // ---- prefetch tile 0 into registers
  float4 ka, kb2;
  float va[8];
  {
    const float* kp = K + (size_t)krow * ROWSTR + base + kcol;
    ka  = *(const float4*)(kp);
    kb2 = *(const float4*)(kp + 4);
    const float* vp = V + (size_t)(tg * 8) * ROWSTR + base + dcol;
#pragma unroll
    for (int i = 0; i < 8; ++i) va[i] = vp[(size_t)i * ROWSTR];
  }

  for (int t0 = 0; t0 < t_end; t0 += KT) {
    __syncthreads();   // previous tile's compute done reading LDS
    // ---- write staged regs -> LDS (bf16)
    {
      short* kd = lds_k + krow * KSTR + kcol;
      uint2 w0; w0.x = pk2(ka.x, ka.y);  w0.y = pk2(ka.z, ka.w);
      uint2 w1; w1.x = pk2(kb2.x, kb2.y); w1.y = pk2(kb2.z, kb2.w);
      *(uint2*)(kd)     = w0;
      *(uint2*)(kd + 4) = w1;
      short* vd = lds_vt + dcol * VTSTR + tg * 8;
      uint2 v0; v0.x = pk2(va[0], va[1]); v0.y = pk2(va[2], va[3]);
      uint2 v1; v1.x = pk2(va[4], va[5]); v1.y = pk2(va[6], va[7]);
      *(uint2*)(vd)     = v0;
      *(uint2*)(vd + 4) = v1;
    }
    __syncthreads();

    // ---- issue next tile's global loads (overlaps with compute below)
    const int tn = t0 + KT;
    if (tn < t_end) {
      const float* kp = K + (size_t)(tn + krow) * ROWSTR + base + kcol;
      ka  = *(const float4*)(kp);
      kb2 = *(const float4*)(kp + 4);
      const float* vp = V + (size_t)(tn + tg * 8) * ROWSTR + base + dcol;
#pragma unroll
      for (int i = 0; i < 8; ++i) va[i] = vp[(size_t)i * ROWSTR];
    }

    if (t0 <= wave_qmax) {   // wave-uniform; barriers stay outside
      // ---- K fragments as A of S^T (m=l16 -> t, k=quad*8+j -> d)
      const short* kp0 = lds_k;
      bf16x8 kA00 = ld8(kp0 + l16 * KSTR + quad * 8);
      bf16x8 kA01 = ld8(kp0 + l16 * KSTR + 32 + quad * 8);
      bf16x8 kA10 = ld8(kp0 + (16 + l16) * KSTR + quad * 8);
      bf16x8 kA11 = ld8(kp0 + (16 + l16) * KSTR + 32 + quad * 8);

      floatx4 z = {0.f,0.f,0.f,0.f};
      floatx4 s0 = __builtin_amdgcn_mfma_f32_16x16x32_bf16(kA00, qf0, z, 0, 0, 0);
      s0 = __builtin_amdgcn_mfma_f32_16x16x32_bf16(kA01, qf1, s0, 0, 0, 0);
      floatx4 s1 = __builtin_amdgcn_mfma_f32_16x16x32_bf16(kA10, qf0, z, 0, 0, 0);
      s1 = __builtin_amdgcn_mfma_f32_16x16x32_bf16(kA11, qf1, s1, 0, 0, 0);

      // ---- p = exp2(s*C1 + C0), causal mask, per-lane l accumulation
      float p0[4], p1[4];
#pragma unroll
      for (int r = 0; r < 4; ++r) {
        const int ta = t0 + quad * 4 + r;
        float e0 = __builtin_amdgcn_exp2f(fmaf(s0[r], C1, C0));
        float e1 = __builtin_amdgcn_exp2f(fmaf(s1[r], C1, C0));
        p0[r] = (ta <= qrow)      ? e0 : 0.f;
        p1[r] = (ta + 16 <= qrow) ? e1 : 0.f;
        lsum += p0[r] + p1[r];
      }

      // ---- P stored [q][t] (per-wave region): 2 vector b64 writes
      short* pw = lds_p + wave * (16 * PSTR) + l16 * PSTR;
      uint2 pa; pa.x = pk2(p0[0], p0[1]); pa.y = pk2(p0[2], p0[3]);
      uint2 pb; pb.x = pk2(p1[0], p1[1]); pb.y = pk2(p1[2], p1[3]);
      *(uint2*)(pw + quad * 4)      = pa;
      *(uint2*)(pw + 16 + quad * 4) = pb;
      asm volatile("s_waitcnt lgkmcnt(0)" ::: "memory");  // per-wave LDS RAW

      // ---- B-frag of PV: n=l16 -> q (own row), k=quad*8+j -> t
      bf16x8 pf = ld8(pw + quad * 8);

      // ---- A-frags from V^T (m=l16 -> d within chunk, k -> t)
      const short* vb = lds_vt;
      bf16x8 vf0 = ld8(vb + (l16)      * VTSTR + quad * 8);
      bf16x8 vf1 = ld8(vb + (16 + l16) * VTSTR + quad * 8);
      bf16x8 vf2 = ld8(vb + (32 + l16) * VTSTR + quad * 8);
      bf16x8 vf3 = ld8(vb + (48 + l16) * VTSTR + quad * 8);

      o0 = __builtin_amdgcn_mfma_f32_16x16x32_bf16(vf0, pf, o0, 0, 0, 0);
      o1 = __builtin_amdgcn_mfma_f32_16x16x32_bf16(vf1, pf, o1, 0, 0, 0);
      o2 = __builtin_amdgcn_mfma_f32_16x16x32_bf16(vf2, pf, o2, 0, 0, 0);
      o3 = __builtin_amdgcn_mfma_f32_16x16x32_bf16(vf3, pf, o3, 0, 0, 0);
    }
  }

  // ---- epilogue: reduce l across quads (same l16 = same q-row), write O
  lsum += __shfl_xor(lsum, 16);
  lsum += __shfl_xor(lsum, 32);
  const float inv = 1.0f / lsum;

  float* op = O + (size_t)qrow * ROWSTR + base + quad * 4;
  float4 w0 = {o0[0]*inv, o0[1]*inv, o0[2]*inv, o0[3]*inv};
  float4 w1 = {o1[0]*inv, o1[1]*inv, o1[2]*inv, o1[3]*inv};
  float4 w2 = {o2[0]*inv, o2[1]*inv, o2[2]*inv, o2[3]*inv};
  float4 w3 = {o3[0]*inv, o3[1]*inv, o3[2]*inv, o3[3]*inv};
  *(float4*)(op)      = w0;   // d = 0..15 chunk, rows quad*4+r
  *(float4*)(op + 16) = w1;
  *(float4*)(op + 32) = w2;
  *(float4*)(op + 48) = w3;
}

extern "C" void kernel_launch(void* const* d_in, const int* in_sizes, int n_in,
                              void* d_out, int out_size, void* d_ws, size_t ws_size,
                              hipStream_t stream) {
  (void)in_sizes; (void)n_in; (void)out_size; (void)d_ws; (void)ws_size;
  const float* Q = (const float*)d_in[0];
  const float* K = (const float*)d_in[1];
  const float* V = (const float*)d_in[2];
  float* O = (float*)d_out;

  dim3 grid(2048 / QT, 32, 1);   // 32 q-tiles x 32 (b,h) = 1024 blocks
  dim3 block(256, 1, 1);
  fattn_kernel<<<grid, block, 0, stream>>>(Q, K, V, O);
}

// Round 8
// 162.545 us; speedup vs baseline: 1.8103x; 1.0518x over previous
//
#include <hip/hip_runtime.h>
#include <hip/hip_bf16.h>

// Causal fused attention, S=2048, B=2, H=16, D=64. FP32 in/out, bf16 MFMA.
// elem(s,bh,d) = s*2048 + bh*64 + d.
//
// Round-8 structure:
//  - 512-thread blocks (8 waves). Waves 0-3 = half 0 of KV range, waves 4-7 =
//    half 1 (equal tile counts -> lockstep barriers). Fixed-shift exp makes
//    partials additive; epilogue combines halves via LDS (overlaid on lds_v).
//  - Single barrier per K-tile, double-buffered K/V LDS.
//  - P (C-layout) -> B-operand layout via per-wave LDS round-trip (PROVEN in
//    round 6; ds_bpermute is per-32-lane-half on CDNA and CANNOT do this
//    cross-half transpose -- round-7 bug).
//  - S^T = K·Q^T, O^T = V^T·P; per-lane softmax rows, l reduced once at end.

typedef __attribute__((ext_vector_type(8))) short bf16x8;
typedef __attribute__((ext_vector_type(4))) float floatx4;

#define ROWSTR 2048
#define C1 (0.125f * 1.44269504088896f)   // SCALE * log2(e)
#define C0 (-17.3123404906676f)           // fixed shift (no running max)
#define QT 64
#define KT 32
#define KSTR  68   // K row stride (shorts): measured 0 bank conflicts (r6)
#define VTSTR 36   // V^T row stride: measured 0 bank conflicts (r6)
#define PSTR  36   // P row stride (r6-proven)

__device__ __forceinline__ short f2bf(float x) {
  return __builtin_bit_cast(short, __float2bfloat16(x));
}
__device__ __forceinline__ unsigned pk2(float a, float b) {
  return (unsigned)(unsigned short)f2bf(a) |
         ((unsigned)(unsigned short)f2bf(b) << 16);
}
__device__ __forceinline__ bf16x8 ld8(const short* p) {  // two ds_read_b64
  union { bf16x8 v; uint2 u[2]; } r;
  r.u[0] = *(const uint2*)(p);
  r.u[1] = *(const uint2*)(p + 4);
  return r.v;
}

__global__ __launch_bounds__(512, 6)
void fattn_kernel(const float* __restrict__ Q,
                  const float* __restrict__ K,
                  const float* __restrict__ V,
                  float* __restrict__ O) {
  __shared__ __align__(16) short lds_k[2*2*KT*KSTR];    // [half][par] 17408 B
  __shared__ __align__(16) short lds_v[2*2*64*VTSTR];   // [half][par] 18432 B
  __shared__ __align__(16) short lds_p[8*16*PSTR];      // per-wave P, 9216 B

  const int tid  = threadIdx.x;
  const int wave = tid >> 6;
  const int half = wave >> 2;     // t-range half
  const int w    = wave & 3;      // q-slab (16 rows) within tile
  const int lane = tid & 63;
  const int l16  = lane & 15;
  const int quad = lane >> 4;

  const int id    = blockIdx.x;
  const int bh    = id & 31;               // spread bh over XCDs
  const int qtile = 31 - (id >> 5);        // longest blocks first
  const int qb    = qtile * QT;
  const size_t base = (size_t)bh * 64;

  const int n      = qtile + 1;            // KT-tiles per half
  const int t_base = half * KT * n;        // half 0: [0,32n), half 1: [32n,64n)

  const int qrow      = qb + w * 16 + l16;
  const int wave_qmax = qb + w * 16 + 15;

  // ---- Q fragments (B-operand of S^T: n=l16 -> q, k=quad*8+j -> d)
  bf16x8 qf0, qf1;
  {
    const float* qp = Q + (size_t)qrow * ROWSTR + base + quad * 8;
    float4 a0 = *(const float4*)(qp);
    float4 a1 = *(const float4*)(qp + 4);
    float4 b0 = *(const float4*)(qp + 32);
    float4 b1 = *(const float4*)(qp + 36);
    qf0[0]=f2bf(a0.x); qf0[1]=f2bf(a0.y); qf0[2]=f2bf(a0.z); qf0[3]=f2bf(a0.w);
    qf0[4]=f2bf(a1.x); qf0[5]=f2bf(a1.y); qf0[6]=f2bf(a1.z); qf0[7]=f2bf(a1.w);
    qf1[0]=f2bf(b0.x); qf1[1]=f2bf(b0.y); qf1[2]=f2bf(b0.z); qf1[3]=f2bf(b0.w);
    qf1[4]=f2bf(b1.x); qf1[5]=f2bf(b1.y); qf1[6]=f2bf(b1.z); qf1[7]=f2bf(b1.w);
  }

  floatx4 o0 = {0.f,0.f,0.f,0.f}, o1 = o0, o2 = o0, o3 = o0;  // O^T partial
  float lsum = 0.f;

  // staging roles within the half's 256 threads
  const int htid = tid & 255;
  const int krow = htid >> 3;          // 0..31
  const int kcol = (htid & 7) * 8;     // 0..56
  const int dcol = htid & 63;          // V^T row (d)
  const int tg   = (htid >> 6) & 3;    // t-group of 8

  short* kbuf0 = lds_k + (half*2 + 0) * (KT*KSTR);
  short* kbuf1 = lds_k + (half*2 + 1) * (KT*KSTR);
  short* vbuf0 = lds_v + (half*2 + 0) * (64*VTSTR);
  short* vbuf1 = lds_v + (half*2 + 1) * (64*VTSTR);

  float4 ka, kb2; float va[8];
  auto load_regs = [&](int t0) {
    const float* kp = K + (size_t)(t0 + krow) * ROWSTR + base + kcol;
    ka  = *(const float4*)(kp);
    kb2 = *(const float4*)(kp + 4);
    const float* vp = V + (size_t)(t0 + tg * 8) * ROWSTR + base + dcol;
#pragma unroll
    for (int j = 0; j < 8; ++j) va[j] = vp[(size_t)j * ROWSTR];
  };
  auto write_lds = [&](short* kd0, short* vd0) {
    short* kd = kd0 + krow * KSTR + kcol;
    uint2 w0; w0.x = pk2(ka.x, ka.y);   w0.y = pk2(ka.z, ka.w);
    uint2 w1; w1.x = pk2(kb2.x, kb2.y); w1.y = pk2(kb2.z, kb2.w);
    *(uint2*)(kd)     = w0;
    *(uint2*)(kd + 4) = w1;
    short* vd = vd0 + dcol * VTSTR + tg * 8;
    uint2 v0; v0.x = pk2(va[0], va[1]); v0.y = pk2(va[2], va[3]);
    uint2 v1; v1.x = pk2(va[4], va[5]); v1.y = pk2(va[6], va[7]);
    *(uint2*)(vd)     = v0;
    *(uint2*)(vd + 4) = v1;
  };

  // ---- prologue
  load_regs(t_base);
  write_lds(kbuf0, vbuf0);
  if (n > 1) load_regs(t_base + KT);

  // ---- K-loop: ONE barrier per tile (double-buffered LDS)
  for (int i = 0; i < n; ++i) {
    __syncthreads();
    const int par = i & 1;
    const int t0  = t_base + KT * i;

    if (t0 <= wave_qmax) {   // wave-uniform causal skip
      const short* kb = par ? kbuf1 : kbuf0;
      const short* vb = par ? vbuf1 : vbuf0;

      bf16x8 kA00 = ld8(kb + l16 * KSTR + quad * 8);
      bf16x8 kA01 = ld8(kb + l16 * KSTR + 32 + quad * 8);
      bf16x8 kA10 = ld8(kb + (16 + l16) * KSTR + quad * 8);
      bf16x8 kA11 = ld8(kb + (16 + l16) * KSTR + 32 + quad * 8);

      floatx4 z = {0.f,0.f,0.f,0.f};
      floatx4 s0 = __builtin_amdgcn_mfma_f32_16x16x32_bf16(kA00, qf0, z, 0, 0, 0);
      s0 = __builtin_amdgcn_mfma_f32_16x16x32_bf16(kA01, qf1, s0, 0, 0, 0);
      floatx4 s1 = __builtin_amdgcn_mfma_f32_16x16x32_bf16(kA10, qf0, z, 0, 0, 0);
      s1 = __builtin_amdgcn_mfma_f32_16x16x32_bf16(kA11, qf1, s1, 0, 0, 0);

      float p0[4], p1[4];
#pragma unroll
      for (int r = 0; r < 4; ++r) {
        const int ta = t0 + quad * 4 + r;
        float e0 = __builtin_amdgcn_exp2f(fmaf(s0[r], C1, C0));
        float e1 = __builtin_amdgcn_exp2f(fmaf(s1[r], C1, C0));
        p0[r] = (ta <= qrow)      ? e0 : 0.f;
        p1[r] = (ta + 16 <= qrow) ? e1 : 0.f;
        lsum += p0[r] + p1[r];
      }

      // ---- P: C-layout -> B-operand layout via per-wave LDS (r6-proven)
      short* pw = lds_p + wave * (16 * PSTR) + l16 * PSTR;
      uint2 pa; pa.x = pk2(p0[0], p0[1]); pa.y = pk2(p0[2], p0[3]);
      uint2 pb; pb.x = pk2(p1[0], p1[1]); pb.y = pk2(p1[2], p1[3]);
      *(uint2*)(pw + quad * 4)      = pa;
      *(uint2*)(pw + 16 + quad * 4) = pb;
      asm volatile("s_waitcnt lgkmcnt(0)" ::: "memory");  // per-wave LDS RAW

      bf16x8 pf = ld8(pw + quad * 8);

      bf16x8 vf0 = ld8(vb + (l16)      * VTSTR + quad * 8);
      bf16x8 vf1 = ld8(vb + (16 + l16) * VTSTR + quad * 8);
      bf16x8 vf2 = ld8(vb + (32 + l16) * VTSTR + quad * 8);
      bf16x8 vf3 = ld8(vb + (48 + l16) * VTSTR + quad * 8);

      o0 = __builtin_amdgcn_mfma_f32_16x16x32_bf16(vf0, pf, o0, 0, 0, 0);
      o1 = __builtin_amdgcn_mfma_f32_16x16x32_bf16(vf1, pf, o1, 0, 0, 0);
      o2 = __builtin_amdgcn_mfma_f32_16x16x32_bf16(vf2, pf, o2, 0, 0, 0);
      o3 = __builtin_amdgcn_mfma_f32_16x16x32_bf16(vf3, pf, o3, 0, 0, 0);
    }

    if (i + 1 < n) {
      write_lds(par ? kbuf0 : kbuf1, par ? vbuf0 : vbuf1);  // tile i+1
      if (i + 2 < n) load_regs(t_base + KT * (i + 2));
    }
  }

  // ---- reduce l over quads (row-replicated per l16)
  lsum += __shfl_xor(lsum, 16);
  lsum += __shfl_xor(lsum, 32);

  // ---- combine halves through LDS (partials additive: fixed-shift exp).
  // Buffer overlays lds_v (17408 B needed <= 18432 B; K-loop reads done).
  __syncthreads();
  float* shO = (float*)lds_v;            // 4096 floats (16 KB)
  float* shL = (float*)lds_v + 4096;     // 256 floats
  const int slot = (w * 64 + lane) * 16;
  if (half == 1) {
    float4 t0v = {o0[0], o0[1], o0[2], o0[3]};
    float4 t1v = {o1[0], o1[1], o1[2], o1[3]};
    float4 t2v = {o2[0], o2[1], o2[2], o2[3]};
    float4 t3v = {o3[0], o3[1], o3[2], o3[3]};
    *(float4*)(shO + slot)      = t0v;
    *(float4*)(shO + slot + 4)  = t1v;
    *(float4*)(shO + slot + 8)  = t2v;
    *(float4*)(shO + slot + 12) = t3v;
    shL[w * 64 + lane] = lsum;
  }
  __syncthreads();
  if (half == 0) {
    float4 a0v = *(float4*)(shO + slot);
    float4 a1v = *(float4*)(shO + slot + 4);
    float4 a2v = *(float4*)(shO + slot + 8);
    float4 a3v = *(float4*)(shO + slot + 12);
    const float lt = lsum + shL[w * 64 + lane];
    const float inv = 1.0f / lt;
    float* op = O + (size_t)qrow * ROWSTR + base + quad * 4;
    float4 w0v = {(o0[0]+a0v.x)*inv, (o0[1]+a0v.y)*inv, (o0[2]+a0v.z)*inv, (o0[3]+a0v.w)*inv};
    float4 w1v = {(o1[0]+a1v.x)*inv, (o1[1]+a1v.y)*inv, (o1[2]+a1v.z)*inv, (o1[3]+a1v.w)*inv};
    float4 w2v = {(o2[0]+a2v.x)*inv, (o2[1]+a2v.y)*inv, (o2[2]+a2v.z)*inv, (o2[3]+a2v.w)*inv};
    float4 w3v = {(o3[0]+a3v.x)*inv, (o3[1]+a3v.y)*inv, (o3[2]+a3v.z)*inv, (o3[3]+a3v.w)*inv};
    *(float4*)(op)      = w0v;
    *(float4*)(op + 16) = w1v;
    *(float4*)(op + 32) = w2v;
    *(float4*)(op + 48) = w3v;
  }
}

extern "C" void kernel_launch(void* const* d_in, const int* in_sizes, int n_in,
                              void* d_out, int out_size, void* d_ws, size_t ws_size,
                              hipStream_t stream) {
  (void)in_sizes; (void)n_in; (void)out_size; (void)d_ws; (void)ws_size;
  const float* Q = (const float*)d_in[0];
  const float* K = (const float*)d_in[1];
  const float* V = (const float*)d_in[2];
  float* O = (float*)d_out;

  dim3 grid(1024, 1, 1);     // 32 qtiles x 32 bh
  dim3 block(512, 1, 1);     // 8 waves: 2 t-halves x 4 q-slabs
  fattn_kernel<<<grid, block, 0, stream>>>(Q, K, V, O);
}

// Round 9
// 154.815 us; speedup vs baseline: 1.9006x; 1.0499x over previous
//
#include <hip/hip_runtime.h>
#include <hip/hip_bf16.h>

// Causal fused attention, S=2048, B=2, H=16, D=64. FP32 in/out, bf16 MFMA.
// elem(s,bh,d) = s*2048 + bh*64 + d.
//
// Round-9 = round-8 (passing) + VALU-overhead reduction:
//  - pk2 via one v_perm_b32 (truncating fp32->bf16 pack; inputs are
//    bf16-rounded so truncation==RNE for K/V; P truncation adds <=2^-8 rel).
//  - Running global pointers in the K-loop (no per-tile 64-bit address mul).
// Structure: 512-thread blocks, 2 KV-halves x 4 q-slabs, single barrier per
// tile, double-buffered K/V LDS, P transpose via per-wave LDS round-trip,
// fixed-shift exp, additive half-combine in epilogue.

typedef __attribute__((ext_vector_type(8))) short bf16x8;
typedef __attribute__((ext_vector_type(4))) float floatx4;

#define ROWSTR 2048
#define C1 (0.125f * 1.44269504088896f)   // SCALE * log2(e)
#define C0 (-17.3123404906676f)           // fixed shift (no running max)
#define QT 64
#define KT 32
#define KSTR  68   // K row stride (shorts): measured 0 bank conflicts (r6)
#define VTSTR 36   // V^T row stride: measured 0 bank conflicts (r6)
#define PSTR  36   // P row stride (r6-proven)

__device__ __forceinline__ short f2bf(float x) {
  return __builtin_bit_cast(short, __float2bfloat16(x));
}
// pack two fp32 -> two bf16 by byte-select (1x v_perm_b32). Truncation:
// exact for bf16-rounded inputs; <=2^-8 rel error otherwise.
__device__ __forceinline__ unsigned pk2(float a, float b) {
  return __builtin_amdgcn_perm(__builtin_bit_cast(unsigned, b),
                               __builtin_bit_cast(unsigned, a),
                               0x07060302u);
}
__device__ __forceinline__ bf16x8 ld8(const short* p) {  // two ds_read_b64
  union { bf16x8 v; uint2 u[2]; } r;
  r.u[0] = *(const uint2*)(p);
  r.u[1] = *(const uint2*)(p + 4);
  return r.v;
}

__global__ __launch_bounds__(512, 6)
void fattn_kernel(const float* __restrict__ Q,
                  const float* __restrict__ K,
                  const float* __restrict__ V,
                  float* __restrict__ O) {
  __shared__ __align__(16) short lds_k[2*2*KT*KSTR];    // [half][par] 17408 B
  __shared__ __align__(16) short lds_v[2*2*64*VTSTR];   // [half][par] 18432 B
  __shared__ __align__(16) short lds_p[8*16*PSTR];      // per-wave P, 9216 B

  const int tid  = threadIdx.x;
  const int wave = tid >> 6;
  const int half = wave >> 2;     // t-range half
  const int w    = wave & 3;      // q-slab (16 rows) within tile
  const int lane = tid & 63;
  const int l16  = lane & 15;
  const int quad = lane >> 4;

  const int id    = blockIdx.x;
  const int bh    = id & 31;               // spread bh over XCDs
  const int qtile = 31 - (id >> 5);        // longest blocks first
  const int qb    = qtile * QT;
  const size_t base = (size_t)bh * 64;

  const int n      = qtile + 1;            // KT-tiles per half
  const int t_base = half * KT * n;        // half 0: [0,32n), half 1: [32n,64n)

  const int qrow      = qb + w * 16 + l16;
  const int wave_qmax = qb + w * 16 + 15;

  // ---- Q fragments (B-operand of S^T: n=l16 -> q, k=quad*8+j -> d)
  bf16x8 qf0, qf1;
  {
    const float* qp = Q + (size_t)qrow * ROWSTR + base + quad * 8;
    float4 a0 = *(const float4*)(qp);
    float4 a1 = *(const float4*)(qp + 4);
    float4 b0 = *(const float4*)(qp + 32);
    float4 b1 = *(const float4*)(qp + 36);
    qf0[0]=f2bf(a0.x); qf0[1]=f2bf(a0.y); qf0[2]=f2bf(a0.z); qf0[3]=f2bf(a0.w);
    qf0[4]=f2bf(a1.x); qf0[5]=f2bf(a1.y); qf0[6]=f2bf(a1.z); qf0[7]=f2bf(a1.w);
    qf1[0]=f2bf(b0.x); qf1[1]=f2bf(b0.y); qf1[2]=f2bf(b0.z); qf1[3]=f2bf(b0.w);
    qf1[4]=f2bf(b1.x); qf1[5]=f2bf(b1.y); qf1[6]=f2bf(b1.z); qf1[7]=f2bf(b1.w);
  }

  floatx4 o0 = {0.f,0.f,0.f,0.f}, o1 = o0, o2 = o0, o3 = o0;  // O^T partial
  float lsum = 0.f;

  // staging roles within the half's 256 threads
  const int htid = tid & 255;
  const int krow = htid >> 3;          // 0..31
  const int kcol = (htid & 7) * 8;     // 0..56
  const int dcol = htid & 63;          // V^T row (d)
  const int tg   = (htid >> 6) & 3;    // t-group of 8

  short* kbuf0 = lds_k + (half*2 + 0) * (KT*KSTR);
  short* kbuf1 = lds_k + (half*2 + 1) * (KT*KSTR);
  short* vbuf0 = lds_v + (half*2 + 0) * (64*VTSTR);
  short* vbuf1 = lds_v + (half*2 + 1) * (64*VTSTR);

  // running global pointers (advance by KT rows per staged tile)
  const float* kp_run = K + (size_t)(t_base + krow) * ROWSTR + base + kcol;
  const float* vp_run = V + (size_t)(t_base + tg * 8) * ROWSTR + base + dcol;
  const size_t step = (size_t)KT * ROWSTR;

  float4 ka, kb2; float va[8];
  auto load_regs = [&]() {
    ka  = *(const float4*)(kp_run);
    kb2 = *(const float4*)(kp_run + 4);
#pragma unroll
    for (int j = 0; j < 8; ++j) va[j] = vp_run[(size_t)j * ROWSTR];
    kp_run += step;
    vp_run += step;
  };
  auto write_lds = [&](short* kd0, short* vd0) {
    short* kd = kd0 + krow * KSTR + kcol;
    uint2 w0; w0.x = pk2(ka.x, ka.y);   w0.y = pk2(ka.z, ka.w);
    uint2 w1; w1.x = pk2(kb2.x, kb2.y); w1.y = pk2(kb2.z, kb2.w);
    *(uint2*)(kd)     = w0;
    *(uint2*)(kd + 4) = w1;
    short* vd = vd0 + dcol * VTSTR + tg * 8;
    uint2 v0; v0.x = pk2(va[0], va[1]); v0.y = pk2(va[2], va[3]);
    uint2 v1; v1.x = pk2(va[4], va[5]); v1.y = pk2(va[6], va[7]);
    *(uint2*)(vd)     = v0;
    *(uint2*)(vd + 4) = v1;
  };

  // ---- prologue
  load_regs();                 // tile 0
  write_lds(kbuf0, vbuf0);
  if (n > 1) load_regs();      // tile 1

  // ---- K-loop: ONE barrier per tile (double-buffered LDS)
  for (int i = 0; i < n; ++i) {
    __syncthreads();
    const int par = i & 1;
    const int t0  = t_base + KT * i;

    if (t0 <= wave_qmax) {   // wave-uniform causal skip
      const short* kb = par ? kbuf1 : kbuf0;
      const short* vb = par ? vbuf1 : vbuf0;

      bf16x8 kA00 = ld8(kb + l16 * KSTR + quad * 8);
      bf16x8 kA01 = ld8(kb + l16 * KSTR + 32 + quad * 8);
      bf16x8 kA10 = ld8(kb + (16 + l16) * KSTR + quad * 8);
      bf16x8 kA11 = ld8(kb + (16 + l16) * KSTR + 32 + quad * 8);

      floatx4 z = {0.f,0.f,0.f,0.f};
      floatx4 s0 = __builtin_amdgcn_mfma_f32_16x16x32_bf16(kA00, qf0, z, 0, 0, 0);
      s0 = __builtin_amdgcn_mfma_f32_16x16x32_bf16(kA01, qf1, s0, 0, 0, 0);
      floatx4 s1 = __builtin_amdgcn_mfma_f32_16x16x32_bf16(kA10, qf0, z, 0, 0, 0);
      s1 = __builtin_amdgcn_mfma_f32_16x16x32_bf16(kA11, qf1, s1, 0, 0, 0);

      float p0[4], p1[4];
#pragma unroll
      for (int r = 0; r < 4; ++r) {
        const int ta = t0 + quad * 4 + r;
        float e0 = __builtin_amdgcn_exp2f(fmaf(s0[r], C1, C0));
        float e1 = __builtin_amdgcn_exp2f(fmaf(s1[r], C1, C0));
        p0[r] = (ta <= qrow)      ? e0 : 0.f;
        p1[r] = (ta + 16 <= qrow) ? e1 : 0.f;
        lsum += p0[r] + p1[r];
      }

      // ---- P: C-layout -> B-operand layout via per-wave LDS (r6-proven)
      short* pw = lds_p + wave * (16 * PSTR) + l16 * PSTR;
      uint2 pa; pa.x = pk2(p0[0], p0[1]); pa.y = pk2(p0[2], p0[3]);
      uint2 pb; pb.x = pk2(p1[0], p1[1]); pb.y = pk2(p1[2], p1[3]);
      *(uint2*)(pw + quad * 4)      = pa;
      *(uint2*)(pw + 16 + quad * 4) = pb;
      asm volatile("s_waitcnt lgkmcnt(0)" ::: "memory");  // per-wave LDS RAW

      bf16x8 pf = ld8(pw + quad * 8);

      bf16x8 vf0 = ld8(vb + (l16)      * VTSTR + quad * 8);
      bf16x8 vf1 = ld8(vb + (16 + l16) * VTSTR + quad * 8);
      bf16x8 vf2 = ld8(vb + (32 + l16) * VTSTR + quad * 8);
      bf16x8 vf3 = ld8(vb + (48 + l16) * VTSTR + quad * 8);

      o0 = __builtin_amdgcn_mfma_f32_16x16x32_bf16(vf0, pf, o0, 0, 0, 0);
      o1 = __builtin_amdgcn_mfma_f32_16x16x32_bf16(vf1, pf, o1, 0, 0, 0);
      o2 = __builtin_amdgcn_mfma_f32_16x16x32_bf16(vf2, pf, o2, 0, 0, 0);
      o3 = __builtin_amdgcn_mfma_f32_16x16x32_bf16(vf3, pf, o3, 0, 0, 0);
    }

    if (i + 1 < n) {
      write_lds(par ? kbuf0 : kbuf1, par ? vbuf0 : vbuf1);  // tile i+1
      if (i + 2 < n) load_regs();                           // tile i+2
    }
  }

  // ---- reduce l over quads (row-replicated per l16)
  lsum += __shfl_xor(lsum, 16);
  lsum += __shfl_xor(lsum, 32);

  // ---- combine halves through LDS (partials additive: fixed-shift exp).
  // Buffer overlays lds_v (17408 B needed <= 18432 B; K-loop reads done).
  __syncthreads();
  float* shO = (float*)lds_v;            // 4096 floats (16 KB)
  float* shL = (float*)lds_v + 4096;     // 256 floats
  const int slot = (w * 64 + lane) * 16;
  if (half == 1) {
    float4 t0v = {o0[0], o0[1], o0[2], o0[3]};
    float4 t1v = {o1[0], o1[1], o1[2], o1[3]};
    float4 t2v = {o2[0], o2[1], o2[2], o2[3]};
    float4 t3v = {o3[0], o3[1], o3[2], o3[3]};
    *(float4*)(shO + slot)      = t0v;
    *(float4*)(shO + slot + 4)  = t1v;
    *(float4*)(shO + slot + 8)  = t2v;
    *(float4*)(shO + slot + 12) = t3v;
    shL[w * 64 + lane] = lsum;
  }
  __syncthreads();
  if (half == 0) {
    float4 a0v = *(float4*)(shO + slot);
    float4 a1v = *(float4*)(shO + slot + 4);
    float4 a2v = *(float4*)(shO + slot + 8);
    float4 a3v = *(float4*)(shO + slot + 12);
    const float lt = lsum + shL[w * 64 + lane];
    const float inv = 1.0f / lt;
    float* op = O + (size_t)qrow * ROWSTR + base + quad * 4;
    float4 w0v = {(o0[0]+a0v.x)*inv, (o0[1]+a0v.y)*inv, (o0[2]+a0v.z)*inv, (o0[3]+a0v.w)*inv};
    float4 w1v = {(o1[0]+a1v.x)*inv, (o1[1]+a1v.y)*inv, (o1[2]+a1v.z)*inv, (o1[3]+a1v.w)*inv};
    float4 w2v = {(o2[0]+a2v.x)*inv, (o2[1]+a2v.y)*inv, (o2[2]+a2v.z)*inv, (o2[3]+a2v.w)*inv};
    float4 w3v = {(o3[0]+a3v.x)*inv, (o3[1]+a3v.y)*inv, (o3[2]+a3v.z)*inv, (o3[3]+a3v.w)*inv};
    *(float4*)(op)      = w0v;
    *(float4*)(op + 16) = w1v;
    *(float4*)(op + 32) = w2v;
    *(float4*)(op + 48) = w3v;
  }
}

extern "C" void kernel_launch(void* const* d_in, const int* in_sizes, int n_in,
                              void* d_out, int out_size, void* d_ws, size_t ws_size,
                              hipStream_t stream) {
  (void)in_sizes; (void)n_in; (void)out_size; (void)d_ws; (void)ws_size;
  const float* Q = (const float*)d_in[0];
  const float* K = (const float*)d_in[1];
  const float* V = (const float*)d_in[2];
  float* O = (float*)d_out;

  dim3 grid(1024, 1, 1);     // 32 qtiles x 32 bh
  dim3 block(512, 1, 1);     // 8 waves: 2 t-halves x 4 q-slabs
  fattn_kernel<<<grid, block, 0, stream>>>(Q, K, V, O);
}

// Round 11
// 124.979 us; speedup vs baseline: 2.3544x; 1.2387x over previous
//
#include <hip/hip_runtime.h>
#include <hip/hip_bf16.h>

// Causal fused attention, S=2048, B=2, H=16, D=64. FP32 in/out, bf16 MFMA.
// elem(s,bh,d) = s*2048 + bh*64 + d.
//
// Round-11 = round-10 with the UB epilogue fixed (real acc arrays; no
// pointer-punning across separate locals -> stores no longer eliminated).
//  - QT=128: 512-thread blocks, 8 waves = 2 KV-halves x 4 waves, each wave
//    owns 32 q-rows (two 16-row slabs A/B). kA frags, vf frags, staging and
//    the barrier are shared across slabs -> per-iteration overhead amortized.
//  - Grid 512 = 16 qtiles x 32 bh, longest-first.
//  - Single barrier per K-tile, double-buffered K/V LDS, per-wave-per-slab
//    P LDS round-trip, fixed-shift exp, additive half-combine epilogue.

typedef __attribute__((ext_vector_type(8))) short bf16x8;
typedef __attribute__((ext_vector_type(4))) float floatx4;

#define ROWSTR 2048
#define C1 (0.125f * 1.44269504088896f)   // SCALE * log2(e)
#define C0 (-17.3123404906676f)           // fixed shift (no running max)
#define QT 128
#define KT 32
#define KSTR  68   // K row stride (shorts): measured 0 bank conflicts (r6)
#define VTSTR 36   // V^T row stride: measured 0 bank conflicts (r6)
#define PSTR  36   // P row stride (r6-proven)

#define KSHORTS (2*2*KT*KSTR)     // 8704
#define VSHORTS (2*2*64*VTSTR)    // 9216
#define PSHORTS (16*16*PSTR)      // 16 slabs x 16 rows -> 9216

__device__ __forceinline__ short f2bf(float x) {
  return __builtin_bit_cast(short, __float2bfloat16(x));
}
// pack two fp32 -> two bf16 by byte-select (1x v_perm_b32)
__device__ __forceinline__ unsigned pk2(float a, float b) {
  return __builtin_amdgcn_perm(__builtin_bit_cast(unsigned, b),
                               __builtin_bit_cast(unsigned, a),
                               0x07060302u);
}
__device__ __forceinline__ bf16x8 ld8(const short* p) {  // two ds_read_b64
  union { bf16x8 v; uint2 u[2]; } r;
  r.u[0] = *(const uint2*)(p);
  r.u[1] = *(const uint2*)(p + 4);
  return r.v;
}
__device__ __forceinline__ bf16x8 cvt8(float4 a, float4 b) {
  union { bf16x8 v; unsigned u[4]; } r;
  r.u[0] = pk2(a.x, a.y); r.u[1] = pk2(a.z, a.w);
  r.u[2] = pk2(b.x, b.y); r.u[3] = pk2(b.z, b.w);
  return r.v;
}

__global__ __launch_bounds__(512, 4)
void fattn_kernel(const float* __restrict__ Q,
                  const float* __restrict__ K,
                  const float* __restrict__ V,
                  float* __restrict__ O) {
  __shared__ __align__(16) short lds_all[KSHORTS + VSHORTS + PSHORTS]; // 54272 B
  short* lds_k = lds_all;
  short* lds_v = lds_all + KSHORTS;
  short* lds_p = lds_all + KSHORTS + VSHORTS;

  const int tid  = threadIdx.x;
  const int wave = tid >> 6;
  const int half = wave >> 2;     // t-range half
  const int w    = wave & 3;      // 32-row q group within tile
  const int lane = tid & 63;
  const int l16  = lane & 15;
  const int quad = lane >> 4;

  const int id    = blockIdx.x;
  const int bh    = id & 31;
  const int qtile = 15 - (id >> 5);        // longest blocks first
  const int qb    = qtile * QT;
  const size_t base = (size_t)bh * 64;

  const int n      = 2 * (qtile + 1);      // KT-tiles per half
  const int t_base = half * KT * n;

  const int qbw   = qb + w * 32;
  const int qrowA = qbw + l16;
  const int qrowB = qbw + 16 + l16;
  const int qmaxA = qbw + 15;
  const int qmaxB = qbw + 31;

  // ---- Q fragments for both slabs (B-operand: n=l16 -> q, k=quad*8+j -> d)
  bf16x8 qfA0, qfA1, qfB0, qfB1;
  {
    const float* qp = Q + (size_t)qrowA * ROWSTR + base + quad * 8;
    qfA0 = cvt8(*(const float4*)(qp),      *(const float4*)(qp + 4));
    qfA1 = cvt8(*(const float4*)(qp + 32), *(const float4*)(qp + 36));
    const float* qp2 = qp + (size_t)16 * ROWSTR;
    qfB0 = cvt8(*(const float4*)(qp2),      *(const float4*)(qp2 + 4));
    qfB1 = cvt8(*(const float4*)(qp2 + 32), *(const float4*)(qp2 + 36));
  }

  const floatx4 zz = {0.f,0.f,0.f,0.f};
  floatx4 accA[4] = {zz, zz, zz, zz};   // real arrays: constant-indexed after
  floatx4 accB[4] = {zz, zz, zz, zz};   // unroll -> stay in registers, no UB
  float lsumA = 0.f, lsumB = 0.f;

  // staging roles within the half's 256 threads
  const int htid = tid & 255;
  const int krow = htid >> 3;          // 0..31
  const int kcol = (htid & 7) * 8;     // 0..56
  const int dcol = htid & 63;          // V^T row (d)
  const int tg   = (htid >> 6) & 3;    // t-group of 8

  short* kbuf0 = lds_k + (half*2 + 0) * (KT*KSTR);
  short* kbuf1 = lds_k + (half*2 + 1) * (KT*KSTR);
  short* vbuf0 = lds_v + (half*2 + 0) * (64*VTSTR);
  short* vbuf1 = lds_v + (half*2 + 1) * (64*VTSTR);

  const float* kp_run = K + (size_t)(t_base + krow) * ROWSTR + base + kcol;
  const float* vp_run = V + (size_t)(t_base + tg * 8) * ROWSTR + base + dcol;
  const size_t step = (size_t)KT * ROWSTR;

  float4 ka, kb2; float va[8];
  auto load_regs = [&]() {
    ka  = *(const float4*)(kp_run);
    kb2 = *(const float4*)(kp_run + 4);
#pragma unroll
    for (int j = 0; j < 8; ++j) va[j] = vp_run[(size_t)j * ROWSTR];
    kp_run += step;
    vp_run += step;
  };
  auto write_lds = [&](short* kd0, short* vd0) {
    short* kd = kd0 + krow * KSTR + kcol;
    uint2 w0; w0.x = pk2(ka.x, ka.y);   w0.y = pk2(ka.z, ka.w);
    uint2 w1; w1.x = pk2(kb2.x, kb2.y); w1.y = pk2(kb2.z, kb2.w);
    *(uint2*)(kd)     = w0;
    *(uint2*)(kd + 4) = w1;
    short* vd = vd0 + dcol * VTSTR + tg * 8;
    uint2 v0; v0.x = pk2(va[0], va[1]); v0.y = pk2(va[2], va[3]);
    uint2 v1; v1.x = pk2(va[4], va[5]); v1.y = pk2(va[6], va[7]);
    *(uint2*)(vd)     = v0;
    *(uint2*)(vd + 4) = v1;
  };

  // ---- prologue
  load_regs();                 // tile 0
  write_lds(kbuf0, vbuf0);
  if (n > 1) load_regs();      // tile 1

  // ---- K-loop: ONE barrier per tile (double-buffered K/V LDS)
  for (int i = 0; i < n; ++i) {
    __syncthreads();
    const int par = i & 1;
    const int t0  = t_base + KT * i;

    if (t0 <= qmaxB) {   // wave-uniform causal skip (slab B = upper rows)
      const short* kb = par ? kbuf1 : kbuf0;
      const short* vb = par ? vbuf1 : vbuf0;

      bf16x8 kA00 = ld8(kb + l16 * KSTR + quad * 8);
      bf16x8 kA01 = ld8(kb + l16 * KSTR + 32 + quad * 8);
      bf16x8 kA10 = ld8(kb + (16 + l16) * KSTR + quad * 8);
      bf16x8 kA11 = ld8(kb + (16 + l16) * KSTR + 32 + quad * 8);

      const bool doA = (t0 <= qmaxA);     // wave-uniform

      // ---- slab B scores + softmax
      floatx4 sB0 = __builtin_amdgcn_mfma_f32_16x16x32_bf16(kA00, qfB0, zz, 0, 0, 0);
      sB0 = __builtin_amdgcn_mfma_f32_16x16x32_bf16(kA01, qfB1, sB0, 0, 0, 0);
      floatx4 sB1 = __builtin_amdgcn_mfma_f32_16x16x32_bf16(kA10, qfB0, zz, 0, 0, 0);
      sB1 = __builtin_amdgcn_mfma_f32_16x16x32_bf16(kA11, qfB1, sB1, 0, 0, 0);

      short* pwB = lds_p + (wave * 2 + 1) * (16 * PSTR) + l16 * PSTR;
      {
        float p0[4], p1[4];
#pragma unroll
        for (int r = 0; r < 4; ++r) {
          const int ta = t0 + quad * 4 + r;
          float e0 = __builtin_amdgcn_exp2f(fmaf(sB0[r], C1, C0));
          float e1 = __builtin_amdgcn_exp2f(fmaf(sB1[r], C1, C0));
          p0[r] = (ta <= qrowB)      ? e0 : 0.f;
          p1[r] = (ta + 16 <= qrowB) ? e1 : 0.f;
          lsumB += p0[r] + p1[r];
        }
        uint2 pa; pa.x = pk2(p0[0], p0[1]); pa.y = pk2(p0[2], p0[3]);
        uint2 pb; pb.x = pk2(p1[0], p1[1]); pb.y = pk2(p1[2], p1[3]);
        *(uint2*)(pwB + quad * 4)      = pa;
        *(uint2*)(pwB + 16 + quad * 4) = pb;
      }

      // ---- slab A scores + softmax (skipped when whole tile masked)
      short* pwA = lds_p + (wave * 2 + 0) * (16 * PSTR) + l16 * PSTR;
      if (doA) {
        floatx4 sA0 = __builtin_amdgcn_mfma_f32_16x16x32_bf16(kA00, qfA0, zz, 0, 0, 0);
        sA0 = __builtin_amdgcn_mfma_f32_16x16x32_bf16(kA01, qfA1, sA0, 0, 0, 0);
        floatx4 sA1 = __builtin_amdgcn_mfma_f32_16x16x32_bf16(kA10, qfA0, zz, 0, 0, 0);
        sA1 = __builtin_amdgcn_mfma_f32_16x16x32_bf16(kA11, qfA1, sA1, 0, 0, 0);
        float p0[4], p1[4];
#pragma unroll
        for (int r = 0; r < 4; ++r) {
          const int ta = t0 + quad * 4 + r;
          float e0 = __builtin_amdgcn_exp2f(fmaf(sA0[r], C1, C0));
          float e1 = __builtin_amdgcn_exp2f(fmaf(sA1[r], C1, C0));
          p0[r] = (ta <= qrowA)      ? e0 : 0.f;
          p1[r] = (ta + 16 <= qrowA) ? e1 : 0.f;
          lsumA += p0[r] + p1[r];
        }
        uint2 pa; pa.x = pk2(p0[0], p0[1]); pa.y = pk2(p0[2], p0[3]);
        uint2 pb; pb.x = pk2(p1[0], p1[1]); pb.y = pk2(p1[2], p1[3]);
        *(uint2*)(pwA + quad * 4)      = pa;
        *(uint2*)(pwA + 16 + quad * 4) = pb;
      }

      asm volatile("s_waitcnt lgkmcnt(0)" ::: "memory");  // per-wave LDS RAW

      // ---- shared V^T fragments
      bf16x8 vf0 = ld8(vb + (l16)      * VTSTR + quad * 8);
      bf16x8 vf1 = ld8(vb + (16 + l16) * VTSTR + quad * 8);
      bf16x8 vf2 = ld8(vb + (32 + l16) * VTSTR + quad * 8);
      bf16x8 vf3 = ld8(vb + (48 + l16) * VTSTR + quad * 8);

      bf16x8 pfB = ld8(pwB + quad * 8);
      accB[0] = __builtin_amdgcn_mfma_f32_16x16x32_bf16(vf0, pfB, accB[0], 0, 0, 0);
      accB[1] = __builtin_amdgcn_mfma_f32_16x16x32_bf16(vf1, pfB, accB[1], 0, 0, 0);
      accB[2] = __builtin_amdgcn_mfma_f32_16x16x32_bf16(vf2, pfB, accB[2], 0, 0, 0);
      accB[3] = __builtin_amdgcn_mfma_f32_16x16x32_bf16(vf3, pfB, accB[3], 0, 0, 0);
      if (doA) {
        bf16x8 pfA = ld8(pwA + quad * 8);
        accA[0] = __builtin_amdgcn_mfma_f32_16x16x32_bf16(vf0, pfA, accA[0], 0, 0, 0);
        accA[1] = __builtin_amdgcn_mfma_f32_16x16x32_bf16(vf1, pfA, accA[1], 0, 0, 0);
        accA[2] = __builtin_amdgcn_mfma_f32_16x16x32_bf16(vf2, pfA, accA[2], 0, 0, 0);
        accA[3] = __builtin_amdgcn_mfma_f32_16x16x32_bf16(vf3, pfA, accA[3], 0, 0, 0);
      }
    }

    if (i + 1 < n) {
      write_lds(par ? kbuf0 : kbuf1, par ? vbuf0 : vbuf1);  // tile i+1
      if (i + 2 < n) load_regs();                           // tile i+2
    }
  }

  // ---- reduce l over quads (row-replicated per l16)
  lsumA += __shfl_xor(lsumA, 16);
  lsumA += __shfl_xor(lsumA, 32);
  lsumB += __shfl_xor(lsumB, 16);
  lsumB += __shfl_xor(lsumB, 32);

  // ---- combine halves through LDS (partials additive: fixed-shift exp).
  // Overlay on lds_all: 8192 floats (32 KB) + 512 floats <= 54272 B.
  __syncthreads();
  float* shO = (float*)lds_all;
  float* shL = (float*)lds_all + 8192;
  const int slotA = ((w * 2 + 0) * 64 + lane) * 16;
  const int slotB = ((w * 2 + 1) * 64 + lane) * 16;

  auto store_part = [&](const floatx4 (&o)[4], int slot, float ls) {
#pragma unroll
    for (int r = 0; r < 4; ++r) {
      float4 t = {o[r][0], o[r][1], o[r][2], o[r][3]};
      *(float4*)(shO + slot + 4 * r) = t;
    }
    shL[slot >> 4] = ls;
  };
  auto combine_store = [&](const floatx4 (&o)[4], int slot, int qrow2, float ls) {
    const float inv = 1.0f / (ls + shL[slot >> 4]);
    float* op = O + (size_t)qrow2 * ROWSTR + base + quad * 4;
#pragma unroll
    for (int r = 0; r < 4; ++r) {
      float4 a = *(float4*)(shO + slot + 4 * r);
      float4 t = {(o[r][0] + a.x) * inv, (o[r][1] + a.y) * inv,
                  (o[r][2] + a.z) * inv, (o[r][3] + a.w) * inv};
      *(float4*)(op + 16 * r) = t;
    }
  };

  if (half == 1) {
    store_part(accA, slotA, lsumA);
    store_part(accB, slotB, lsumB);
  }
  __syncthreads();
  if (half == 0) {
    combine_store(accA, slotA, qrowA, lsumA);
    combine_store(accB, slotB, qrowB, lsumB);
  }
}

extern "C" void kernel_launch(void* const* d_in, const int* in_sizes, int n_in,
                              void* d_out, int out_size, void* d_ws, size_t ws_size,
                              hipStream_t stream) {
  (void)in_sizes; (void)n_in; (void)out_size; (void)d_ws; (void)ws_size;
  const float* Q = (const float*)d_in[0];
  const float* K = (const float*)d_in[1];
  const float* V = (const float*)d_in[2];
  float* O = (float*)d_out;

  dim3 grid(512, 1, 1);      // 16 qtiles x 32 bh
  dim3 block(512, 1, 1);     // 8 waves: 2 t-halves x 4 q-groups of 32 rows
  fattn_kernel<<<grid, block, 0, stream>>>(Q, K, V, O);
}